// Round 2
// baseline (10478.200 us; speedup 1.0000x reference)
//
#include <hip/hip_runtime.h>

#define VN 512
#define EN 32768
#define FN 8
#define HN 128
#define G3 384
#define LN 3
#define NROWS (VN*VN)   // 262144

// ---------------- generic int fill ----------------
__global__ void k_fill(int* __restrict__ p, int val, int n) {
    int i = blockIdx.x * 256 + threadIdx.x;
    if (i < n) p[i] = val;
}

// ---------------- edge canonicalize (+ int64 detection) ----------------
__global__ void k_edges(const void* __restrict__ raw, int* __restrict__ uo, int* __restrict__ vo) {
    const int* r32 = (const int*)raw;
    const long long* r64 = (const long long*)raw;
    int acc = 0;
    #pragma unroll
    for (int i = 1; i < 128; i += 2) acc |= r32[i];
    bool is64 = (acc == 0);
    int e = blockIdx.x * 256 + threadIdx.x;
    if (e < EN) {
        int u, v;
        if (is64) { u = (int)r64[2*e]; v = (int)r64[2*e+1]; }
        else      { u = r32[2*e];      v = r32[2*e+1]; }
        uo[e] = u; vo[e] = v;
    }
}

// ---------------- pack Wcat[l][g][k] (k<128:w1, <256:w2, else w3) and Wsum ----------------
__global__ void k_pack(const float* __restrict__ w1, const float* __restrict__ w2,
                       const float* __restrict__ w3, const float* __restrict__ wih,
                       float* __restrict__ wcat, float* __restrict__ wsum) {
    int t = blockIdx.x * 256 + threadIdx.x;
    if (t < 3*128*384) {
        int l = t / (128*384); int rem = t % (128*384);
        int g = rem / 384;     int k = rem % 384;
        const float* w = (k < 128) ? w1 : (k < 256 ? w2 : w3);
        int kk = k & 127;
        wcat[t] = w[((long)l*128 + g)*128 + kk];
    }
    if (t < 384*128) {
        int g = t / 128, k = t % 128;
        wsum[t] = wih[g*256 + k] + wih[g*256 + 128 + k];
    }
}

// ---------------- winner map: map[u*512+v] = max edge id ----------------
__global__ void k_map(const int* __restrict__ uA, const int* __restrict__ vA, int* __restrict__ map) {
    int e = blockIdx.x * 256 + threadIdx.x;
    if (e < EN) atomicMax(&map[uA[e]*VN + vA[e]], e);
}

// ---------------- embed: x[a,b,h] = sum_f adj[a,b,f]*emb[h,f] ----------------
__global__ __launch_bounds__(256) void k_embed(const float* __restrict__ adj,
                                               const float* __restrict__ emb,
                                               float* __restrict__ x) {
    __shared__ float semb[HN][FN];
    __shared__ float sadj[2][FN];
    int tid = threadIdx.x;
    for (int i = tid; i < HN*FN; i += 256) semb[i/FN][i%FN] = emb[i];
    if (tid < 16) sadj[tid>>3][tid&7] = adj[(long)blockIdx.x*16 + tid];
    __syncthreads();
    int p = tid >> 7;
    int h = tid & 127;
    float acc = 0.f;
    #pragma unroll
    for (int f = 0; f < FN; f++) acc += sadj[p][f]*semb[h][f];
    long row = (long)blockIdx.x*2 + p;
    x[row*HN + h] = acc;
}

// ---------------- col_sum[b,h] = sum_a x[a,b,h]; nnz[b] = count over (a,h) ----------------
__global__ __launch_bounds__(512) void k_colsum(const float* __restrict__ x,
                                                float* __restrict__ colsum, int* __restrict__ nnz) {
    int b = blockIdx.x;
    int tid = threadIdx.x;
    int h = tid & 127, q = tid >> 7;
    float s = 0.f; int c = 0;
    for (int a = q*128; a < q*128 + 128; a++) {
        float v = x[((long)a*VN + b)*HN + h];
        s += v; c += (v != 0.f) ? 1 : 0;
    }
    __shared__ float ss[4][128];
    __shared__ int sc[8];
    ss[q][h] = s;
    #pragma unroll
    for (int off = 32; off; off >>= 1) c += __shfl_down(c, off);
    if ((tid & 63) == 0) sc[tid>>6] = c;
    __syncthreads();
    if (tid < 128) colsum[b*HN + tid] = ss[0][tid]+ss[1][tid]+ss[2][tid]+ss[3][tid];
    if (tid == 0) { int t = 0; for (int i = 0; i < 8; i++) t += sc[i]; nnz[b] = t; }
}

// ---------------- per-edge GEMM inputs: in3 = [x_uv, e_in, e_out] ----------------
__global__ __launch_bounds__(256) void k_edgein(const float* __restrict__ x,
    const int* __restrict__ uA, const int* __restrict__ vA,
    const float* __restrict__ colsum, const int* __restrict__ nnz, float* __restrict__ in3) {
    int w = threadIdx.x >> 6;
    int lane = threadIdx.x & 63;
    int e = blockIdx.x*4 + w;
    int u = uA[e], v = vA[e];
    const float* xuv = x + ((long)u*VN + v)*HN;
    const float* xvu = x + ((long)v*VN + u)*HN;
    float xu0 = xuv[lane], xu1 = xuv[lane+64];
    float xv0 = xvu[lane], xv1 = xvu[lane+64];
    int cnt_vu = __popcll(__ballot(xv0 != 0.f)) + __popcll(__ballot(xv1 != 0.f));
    int cnt_uv = __popcll(__ballot(xu0 != 0.f)) + __popcll(__ballot(xu1 != 0.f));
    float nin  = (float)(nnz[u] - cnt_vu) * (1.f/128.f); if (nin  == 0.f) nin  = 1.f;
    float nout = (float)(nnz[v] - cnt_uv) * (1.f/128.f); if (nout == 0.f) nout = 1.f;
    float* o = in3 + (long)e*G3;
    o[lane]        = xu0;  o[lane+64]      = xu1;
    o[128+lane]    = (colsum[u*HN+lane]    - xv0)/nin;
    o[128+lane+64] = (colsum[u*HN+lane+64] - xv1)/nin;
    o[256+lane]    = (colsum[v*HN+lane]    - xu0)/nout;
    o[256+lane+64] = (colsum[v*HN+lane+64] - xu1)/nout;
}

// ---------------- msg GEMM: msg[e][g] = relu(sum_k in3[e][k]*Wcat[g][k]) ----------------
__global__ __launch_bounds__(256) void k_msggemm(const float* __restrict__ in3,
    const float* __restrict__ wcat, float* __restrict__ msg) {
    const int tid = threadIdx.x;
    const int tn = tid & 31;
    const int tm = tid >> 5;
    const long m0 = (long)blockIdx.x * 64;
    __shared__ float As[64][32];
    __shared__ float Bs[128][32];
    float acc[8][4];
    #pragma unroll
    for (int i = 0; i < 8; i++) { acc[i][0]=acc[i][1]=acc[i][2]=acc[i][3]=0.f; }
    for (int kc = 0; kc < 384; kc += 32) {
        #pragma unroll
        for (int i = 0; i < 2; i++) {
            int idx = tid*2 + i;
            int r = idx >> 3, kv = idx & 7;
            *(float4*)&As[r][kv*4] = *(const float4*)&in3[(m0 + r)*G3 + kc + kv*4];
        }
        #pragma unroll
        for (int i = 0; i < 4; i++) {
            int idx = tid*4 + i;
            int gg = idx >> 3, kv = idx & 7;
            float4 t = *(const float4*)&wcat[(long)gg*G3 + kc + kv*4];
            int kvs = kv ^ ((gg>>2)&7);
            *(float4*)&Bs[gg][kvs*4] = t;
        }
        __syncthreads();
        #pragma unroll
        for (int k4 = 0; k4 < 8; k4++) {
            float4 av[8], bv[4];
            #pragma unroll
            for (int i = 0; i < 8; i++) av[i] = *(const float4*)&As[tm*8+i][k4*4];
            #pragma unroll
            for (int j = 0; j < 4; j++) {
                int n = tn*4 + j;
                int kvs = k4 ^ ((n>>2)&7);
                bv[j] = *(const float4*)&Bs[n][kvs*4];
            }
            #pragma unroll
            for (int i = 0; i < 8; i++)
                #pragma unroll
                for (int j = 0; j < 4; j++)
                    acc[i][j] += av[i].x*bv[j].x + av[i].y*bv[j].y + av[i].z*bv[j].z + av[i].w*bv[j].w;
        }
        __syncthreads();
    }
    #pragma unroll
    for (int i = 0; i < 8; i++) {
        long r = m0 + tm*8 + i;
        float4 o;
        o.x = fmaxf(acc[i][0], 0.f); o.y = fmaxf(acc[i][1], 0.f);
        o.z = fmaxf(acc[i][2], 0.f); o.w = fmaxf(acc[i][3], 0.f);
        *(float4*)&msg[r*HN + tn*4] = o;
    }
}

// ---------------- xi base GEMM (chunk): xi[r-r0][g] = sum_k x[r][k]*Wsum[g][k] + b_ih[g] ----------------
__global__ __launch_bounds__(512) void k_xibase(const float* __restrict__ x,
    const float* __restrict__ wsum, const float* __restrict__ bih, float* __restrict__ xi, int r0) {
    const int tid = threadIdx.x;
    const int tn = tid & 31;
    const int tm = tid >> 5;
    const long m0 = (long)blockIdx.x * 128;        // local row base within chunk
    const int nb = blockIdx.y * 128;
    __shared__ float As[128][32];
    __shared__ float Bs[128][32];
    float acc[8][4];
    #pragma unroll
    for (int i = 0; i < 8; i++) { acc[i][0]=acc[i][1]=acc[i][2]=acc[i][3]=0.f; }
    for (int kc = 0; kc < 128; kc += 32) {
        #pragma unroll
        for (int i = 0; i < 2; i++) {
            int idx = tid*2 + i;
            int r = idx >> 3, kv = idx & 7;
            *(float4*)&As[r][kv*4] = *(const float4*)&x[((long)r0 + m0 + r)*HN + kc + kv*4];
        }
        #pragma unroll
        for (int i = 0; i < 2; i++) {
            int idx = tid*2 + i;
            int gg = idx >> 3, kv = idx & 7;
            float4 t = *(const float4*)&wsum[(long)(nb + gg)*HN + kc + kv*4];
            int kvs = kv ^ ((gg>>2)&7);
            *(float4*)&Bs[gg][kvs*4] = t;
        }
        __syncthreads();
        #pragma unroll
        for (int k4 = 0; k4 < 8; k4++) {
            float4 av[8], bv[4];
            #pragma unroll
            for (int i = 0; i < 8; i++) av[i] = *(const float4*)&As[tm*8+i][k4*4];
            #pragma unroll
            for (int j = 0; j < 4; j++) {
                int n = tn*4 + j;
                int kvs = k4 ^ ((n>>2)&7);
                bv[j] = *(const float4*)&Bs[n][kvs*4];
            }
            #pragma unroll
            for (int i = 0; i < 8; i++)
                #pragma unroll
                for (int j = 0; j < 4; j++)
                    acc[i][j] += av[i].x*bv[j].x + av[i].y*bv[j].y + av[i].z*bv[j].z + av[i].w*bv[j].w;
        }
        __syncthreads();
    }
    float4 bb = *(const float4*)&bih[nb + tn*4];
    #pragma unroll
    for (int i = 0; i < 8; i++) {
        long r = m0 + tm*8 + i;     // local row
        float4 o;
        o.x = acc[i][0]+bb.x; o.y = acc[i][1]+bb.y; o.z = acc[i][2]+bb.z; o.w = acc[i][3]+bb.w;
        *(float4*)&xi[r*G3 + nb + tn*4] = o;
    }
}

// ---------------- xi correction (chunk): xi[row-r0] += (msg[e]-x[row]) @ Wl.T, winners in [r0,r1) ----------------
__global__ __launch_bounds__(384) void k_xicorr(const float* __restrict__ x,
    const float* __restrict__ msg, const int* __restrict__ uA, const int* __restrict__ vA,
    const int* __restrict__ map, const float* __restrict__ wih, float* __restrict__ xi,
    int r0, int r1) {
    int g = threadIdx.x;
    int eb = blockIdx.x * 16;
    float w[128];
    #pragma unroll
    for (int i = 0; i < 128; i += 4) {
        float4 t = *(const float4*)&wih[(long)g*256 + i];
        w[i]=t.x; w[i+1]=t.y; w[i+2]=t.z; w[i+3]=t.w;
    }
    __shared__ float D[16][128];
    __shared__ int rowS[16];
    __shared__ int winS[16];
    if (g < 16) {
        int e = eb + g;
        int r = uA[e]*VN + vA[e];
        rowS[g] = r;
        winS[g] = (map[r] == e && r >= r0 && r < r1) ? 1 : 0;
    }
    __syncthreads();
    for (int idx = g; idx < 16*128; idx += 384) {
        int e = idx >> 7, k = idx & 127;
        D[e][k] = msg[(long)(eb+e)*HN + k] - x[(long)rowS[e]*HN + k];
    }
    __syncthreads();
    for (int e = 0; e < 16; e++) {
        if (!winS[e]) continue;
        float acc = 0.f;
        #pragma unroll
        for (int k4 = 0; k4 < 32; k4++) {
            float4 d = *(const float4*)&D[e][k4*4];
            acc += d.x*w[k4*4] + d.y*w[k4*4+1] + d.z*w[k4*4+2] + d.w*w[k4*4+3];
        }
        xi[((long)rowS[e]-r0)*G3 + g] += acc;
    }
}

// ---------------- GRU scan (chunk): block = a-row a0+blockIdx.x, 512 sequential steps ----------------
// Reads xi (chunk-local rows), writes x rows in place (x == d_out).
__global__ __launch_bounds__(384) void k_scan(const float* __restrict__ xi,
    const float* __restrict__ whh, const float* __restrict__ bhh, float* __restrict__ xout, int a0) {
    int g = threadIdx.x;
    int ab = blockIdx.x;          // chunk-local a index
    float w[128];
    #pragma unroll
    for (int i = 0; i < 128; i += 4) {
        float4 t = *(const float4*)&whh[(long)g*HN + i];
        w[i]=t.x; w[i+1]=t.y; w[i+2]=t.z; w[i+3]=t.w;
    }
    float bh = bhh[g];
    __shared__ float hS[128];
    __shared__ float ghS[384];
    __shared__ float xiS[384];
    if (g < 128) hS[g] = 0.f;
    __syncthreads();
    const float* xirow = xi + (long)ab*VN*G3;
    float* orow = xout + ((long)(a0 + ab)*VN)*HN;
    for (int t = 0; t < VN; t++) {
        float xv = xirow[(long)t*G3 + g];
        float acc = bh;
        #pragma unroll
        for (int k4 = 0; k4 < 32; k4++) {
            float4 hv = *(const float4*)&hS[k4*4];
            acc += hv.x*w[k4*4] + hv.y*w[k4*4+1] + hv.z*w[k4*4+2] + hv.w*w[k4*4+3];
        }
        ghS[g] = acc;
        xiS[g] = xv;
        __syncthreads();
        if (g < 128) {
            float hr = ghS[g], hz = ghS[128+g], hn = ghS[256+g];
            float xr = xiS[g], xz = xiS[128+g], xn = xiS[256+g];
            float r = 1.f/(1.f + expf(-(xr + hr)));
            float z = 1.f/(1.f + expf(-(xz + hz)));
            float n = tanhf(xn + r*hn);
            float hp = hS[g];
            float hnew = (1.f - z)*n + z*hp;
            hS[g] = hnew;
            orow[(long)t*HN + g] = hnew;
        }
        __syncthreads();
    }
}

extern "C" void kernel_launch(void* const* d_in, const int* in_sizes, int n_in,
                              void* d_out, int out_size, void* d_ws, size_t ws_size,
                              hipStream_t stream) {
    const float* adj   = (const float*)d_in[0];
    const void*  edges = d_in[1];
    const float* emb   = (const float*)d_in[2];
    const float* w1    = (const float*)d_in[3];
    const float* w2    = (const float*)d_in[4];
    const float* w3    = (const float*)d_in[5];
    const float* wih   = (const float*)d_in[6];
    const float* whh   = (const float*)d_in[7];
    const float* bih   = (const float*)d_in[8];
    const float* bhh   = (const float*)d_in[9];

    float* x = (float*)d_out;          // x lives in d_out; scan updates it in place

    // ---- workspace layout (adaptive) ----
    char* p = (char*)d_ws;
    auto alloc = [&](size_t bytes) { char* r = p; p += (bytes + 255) & ~255UL; return r; };
    float* in3    = (float*)alloc((size_t)EN*G3*4);        // 50,331,648
    float* msg    = (float*)alloc((size_t)EN*HN*4);        // 16,777,216
    float* colsum = (float*)alloc((size_t)VN*HN*4);
    int*   nnz    = (int*)  alloc((size_t)VN*4);
    int*   map    = (int*)  alloc((size_t)NROWS*4);
    int*   uA     = (int*)  alloc((size_t)EN*4);
    int*   vA     = (int*)  alloc((size_t)EN*4);
    float* wcat   = (float*)alloc((size_t)LN*HN*G3*4);
    float* wsum   = (float*)alloc((size_t)G3*HN*4);
    size_t fixed = (size_t)(p - (char*)d_ws);
    const size_t xi_total = (size_t)NROWS*G3*4;            // 402,653,184
    int nc = 1;
    while (nc < 64 && fixed + xi_total/nc > ws_size) nc <<= 1;
    float* xi = (float*)p;                                 // chunk buffer
    const int RPC = NROWS/nc;                              // rows per chunk
    const int APC = VN/nc;                                 // a-rows per chunk

    k_edges<<<EN/256, 256, 0, stream>>>(edges, uA, vA);
    k_pack<<<(3*128*384 + 255)/256, 256, 0, stream>>>(w1, w2, w3, wih, wcat, wsum);
    k_fill<<<NROWS/256, 256, 0, stream>>>(map, -1, NROWS);
    k_map<<<EN/256, 256, 0, stream>>>(uA, vA, map);
    k_embed<<<NROWS/2, 256, 0, stream>>>(adj, emb, x);

    for (int l = 0; l < LN; l++) {
        k_colsum<<<VN, 512, 0, stream>>>(x, colsum, nnz);
        k_edgein<<<EN/4, 256, 0, stream>>>(x, uA, vA, colsum, nnz, in3);
        k_msggemm<<<EN/64, 256, 0, stream>>>(in3, wcat + (long)l*HN*G3, msg);
        for (int c = 0; c < nc; c++) {
            int r0 = c*RPC;
            k_xibase<<<dim3(RPC/128, 3), 512, 0, stream>>>(x, wsum, bih, xi, r0);
            k_xicorr<<<EN/16, 384, 0, stream>>>(x, msg, uA, vA, map, wih, xi, r0, r0+RPC);
            k_scan<<<APC, 384, 0, stream>>>(xi, whh, bhh, x, c*APC);
        }
    }
}